// Round 1
// baseline (3709.504 us; speedup 1.0000x reference)
//
#include <hip/hip_runtime.h>

// LSTM: H=1024, B=1024, S=128 (T=127 steps), E=6, V=3, C=10.
// R13: persistent single-kernel. R12's lstm_step body (verified) is kept
// intact as the per-step body of a 127-iteration in-kernel loop:
//  - 512 blocks x 256 thr, __launch_bounds__(256,2), 64 KB LDS -> exactly
//    2 blocks/CU on 256 CUs; all blocks co-resident (required: grid barrier).
//  - c state lives in registers for all 127 steps (kills 8 MB/step r/w).
//  - h crosses XCDs: stores are global_store_dwordx2 sc0 sc1 (write-through
//    to L3, device-visible after vmcnt(0)); h READS stay plain/cached, made
//    safe by ONE __builtin_amdgcn_fence(acquire, agent) per block per step.
//  - grid barrier: per-block flag (monotonic step counter) stored sc0 sc1;
//    every block's wave 0 polls all 512 flags with sc0 sc1 loads (bypass L2,
//    no invalidate per poll -- this is what R10/R11 got wrong).
//  - max barrier skew is 1 step => h double-buffer by parity is sufficient.
constexpr int kH = 1024;
constexpr int kB = 1024;
constexpr int kS = 128;
constexpr int kT = 127;
constexpr int kE = 6;
constexpr int kV = 3;
constexpr int kC = 10;

typedef short s16x8 __attribute__((ext_vector_type(8)));
typedef short s16x4 __attribute__((ext_vector_type(4)));
typedef float f32x4 __attribute__((ext_vector_type(4)));
typedef int   i32x2 __attribute__((ext_vector_type(2)));
typedef int   i32x4 __attribute__((ext_vector_type(4)));
typedef unsigned short u16;

__device__ __forceinline__ float b2f(u16 u) {
    return __uint_as_float(((unsigned)u) << 16);
}
__device__ __forceinline__ u16 f2b(float f) {
    unsigned u = __float_as_uint(f);
    return (u16)((u + 0x7FFFu + ((u >> 16) & 1u)) >> 16);   // RNE
}
__device__ __forceinline__ float sigmoid_fast(float x) {
    return 1.0f / (1.0f + __expf(-x));
}
__device__ __forceinline__ float tanh_fast(float x) {
    return 2.0f / (1.0f + __expf(-2.0f * x)) - 1.0f;
}
__device__ __forceinline__ float clamp30(float x) {
    return fminf(fmaxf(x, -30.0f), 30.0f);
}

__device__ __forceinline__ void async_copy16(const u16* g, u16* l) {
    __builtin_amdgcn_global_load_lds(
        (const __attribute__((address_space(1))) void*)g,
        (__attribute__((address_space(3))) void*)l, 16, 0, 0);
}

// ---------------------------------------------------------------------------
// Prep 1: weights fp32 -> bf16, frag-major (identical to R8/R12):
//   grp = (((by*4 + kc)*4 + g)*8 + k0)*64 + lane
//   wsw[grp*8 + j] = W_g[by*16 + (lane&15)][kc*256 + k0*32 + (lane>>4)*8 + j]
// ---------------------------------------------------------------------------
__global__ __launch_bounds__(256) void prep_weights(
    const float* __restrict__ Wgh, const float* __restrict__ Wih,
    const float* __restrict__ Wfh, const float* __restrict__ Woh,
    u16* __restrict__ wsw)
{
    unsigned grp = blockIdx.x * 256 + threadIdx.x;    // 0 .. 2^19-1
    const int lane = grp & 63;
    const int lm   = lane & 15;
    const int quad = lane >> 4;
    const int k0   = (grp >> 6) & 7;
    const int g    = (grp >> 9) & 3;
    const int kc   = (grp >> 11) & 3;
    const int by   = grp >> 13;                       // 0..63
    const float* src = (g == 0) ? Wgh : (g == 1) ? Wih : (g == 2) ? Wfh : Woh;
    const int row = by * 16 + lm;
    const int k   = kc * 256 + k0 * 32 + quad * 8;
    f32x4 v0 = *(const f32x4*)(src + (size_t)row * kH + k);
    f32x4 v1 = *(const f32x4*)(src + (size_t)row * kH + k + 4);
    s16x8 o;
#pragma unroll
    for (int j = 0; j < 4; ++j) o[j] = (short)f2b(v0[j]);
#pragma unroll
    for (int j = 0; j < 4; ++j) o[4 + j] = (short)f2b(v1[j]);
    *(s16x8*)(wsw + (size_t)grp * 8) = o;
}

// ---------------------------------------------------------------------------
// Prep 2: transpose h0 (H,B) fp32 -> hA (B,H) bf16; c0 (H,B) -> cT (B,H) fp32.
// ---------------------------------------------------------------------------
__global__ __launch_bounds__(1024) void prep_hc(
    const float* __restrict__ h0, const float* __restrict__ c0,
    u16* __restrict__ hA, float* __restrict__ cT)
{
    __shared__ float th[32][33];
    __shared__ float tc[32][33];
    int b = blockIdx.x * 32 + threadIdx.x;
    int h = blockIdx.y * 32 + threadIdx.y;
    th[threadIdx.y][threadIdx.x] = h0[(size_t)h * kB + b];
    tc[threadIdx.y][threadIdx.x] = c0[(size_t)h * kB + b];
    __syncthreads();
    int ob = blockIdx.x * 32 + threadIdx.y;
    int oh = blockIdx.y * 32 + threadIdx.x;
    hA[(size_t)ob * kH + oh] = f2b(th[threadIdx.x][threadIdx.y]);
    cT[(size_t)ob * kH + oh] = tc[threadIdx.x][threadIdx.y];
}

// ---------------------------------------------------------------------------
// Prep 3: gate constants repacked as f32x4 (identical to R12), plus zeroing
// the 512 barrier flags (re-zeroed every graph replay, stream-ordered before
// the persistent kernel).
// ---------------------------------------------------------------------------
__global__ __launch_bounds__(256) void prep_q(
    const float* __restrict__ Wgx, const float* __restrict__ Wix,
    const float* __restrict__ Wfx, const float* __restrict__ Wox,
    const float* __restrict__ bg,  const float* __restrict__ bi,
    const float* __restrict__ bf_, const float* __restrict__ bo,
    const float* __restrict__ emb, float* __restrict__ Qp,
    int* __restrict__ flags)
{
    int tid = blockIdx.x * blockDim.x + threadIdx.x;   // 0..4095
    if (tid < 512) flags[tid] = 0;
    if (tid >= 4096) return;
    int g   = tid >> 10;
    int hr4 = (tid & 1023) >> 2;
    int v   = tid & 3;
    const float* Wx = (g == 0) ? Wgx : (g == 1) ? Wix : (g == 2) ? Wfx : Wox;
    const float* bb = (g == 0) ? bg  : (g == 1) ? bi  : (g == 2) ? bf_ : bo;
    f32x4 o;
#pragma unroll
    for (int reg = 0; reg < 4; ++reg) {
        int row = hr4 * 4 + reg;
        float s = bb[row];
        if (v < kV) {
#pragma unroll
            for (int e = 0; e < kE; ++e) s += Wx[row * kE + e] * emb[v * kE + e];
        }
        o[reg] = s;
    }
    *(f32x4*)(Qp + (size_t)tid * 4) = o;
}

// ---------------------------------------------------------------------------
// Persistent LSTM: all 127 timesteps in one launch.
// Grid 512 x 256 thr (2 blocks/CU, all co-resident). Block tile: 16 h-rows x
// 4 gates x 128 cols; wave w: cols [bx*128+32w,+32) (nt=2).
// XCD swizzle: xcd=blk&7, slot=blk>>3, by=xcd*8+(slot&7), bx=slot>>3.
// Weights: 4 K-chunks of 256 staged to LDS (2x32 KB double buffer) per step
// (refetched from L3 after the per-step acquire fence; weights are immutable
// so in-flight staging racing another block's buffer_inv is benign).
// b-operand: depth-6 free-running register ring from global h (cached loads;
// safe because the acquire fence precedes every step's h reads).
// ---------------------------------------------------------------------------
__global__ __launch_bounds__(256, 2) void lstm_persist(
    const u16* __restrict__ wsw, const float* __restrict__ Qp,
    const int* __restrict__ x,
    short* __restrict__ hA, short* __restrict__ hB,
    const float* __restrict__ cT, int* __restrict__ flags)
{
    __shared__ u16 wlds[2][16384];   // 2 x 32 KB

    const int tid  = threadIdx.x;
    const int lane = tid & 63;
    const int wave = tid >> 6;
    const int lm   = lane & 15;
    const int quad = lane >> 4;
    const int blk  = blockIdx.x;
    const int xcd  = blk & 7;
    const int slot = blk >> 3;              // 0..63
    const int by   = xcd * 8 + (slot & 7);  // 0..63
    const int bx   = slot >> 3;             // 0..7
    const int r0 = by * 16;
    const int c0 = bx * 128 + wave * 32;

    const u16* wswblk = wsw + (size_t)by * 65536;   // 4 chunks x 16384 shorts

    // ---- persistent c state: loaded once, lives in registers 127 steps ----
    f32x4 creg[2];
#pragma unroll
    for (int nt = 0; nt < 2; ++nt)
        creg[nt] = *(const f32x4*)(cT +
            (size_t)(c0 + nt * 16 + lm) * kH + r0 + quad * 4);

    const int* xp0 = x + (size_t)(c0 + lm) * kS;
    const int* xp1 = x + (size_t)(c0 + 16 + lm) * kS;
    const int koff = quad * 8;

#pragma unroll 1
    for (int t = 0; t < kT; ++t) {
        const short* hin  = (t & 1) ? hB : hA;
        short*       hout = (t & 1) ? hA : hB;

        // ---- stage chunk 0 (async) ----
#pragma unroll
        for (int rr = 0; rr < 8; ++rr) {
            const int ub = wave * 4096 + rr * 512;   // shorts
            async_copy16(wswblk + ub + lane * 8, &wlds[0][ub]);
        }

        // ---- per-step loads: x -> vv -> Qp vectors (issued early) ----
        int vv[2];
        {
            int v0 = xp0[t]; vv[0] = (v0 < 0) ? 0 : (v0 > kV - 1) ? (kV - 1) : v0;
            int v1 = xp1[t]; vv[1] = (v1 < 0) ? 0 : (v1 > kV - 1) ? (kV - 1) : v1;
        }
        f32x4 qv[2][4];
#pragma unroll
        for (int nt = 0; nt < 2; ++nt)
#pragma unroll
            for (int g = 0; g < 4; ++g)
                qv[nt][g] = *(const f32x4*)(Qp +
                    (size_t)(((g * 256 + by * 4 + quad) * 4 + vv[nt]) * 4));

        // ---- b-ring prologue: slots 0..4 ----
        const short* hrow0 = hin + (size_t)(c0 + lm) * kH + koff;
        const short* hrow1 = hin + (size_t)(c0 + 16 + lm) * kH + koff;
        s16x8 br[6][2];
#pragma unroll
        for (int s = 0; s < 5; ++s) {
            br[s][0] = *(const s16x8*)(hrow0 + s * 32);
            br[s][1] = *(const s16x8*)(hrow1 + s * 32);
        }

        f32x4 acc[4][2];
        const f32x4 zero = {0.f, 0.f, 0.f, 0.f};
#pragma unroll
        for (int g = 0; g < 4; ++g)
#pragma unroll
            for (int n = 0; n < 2; ++n) acc[g][n] = zero;

        asm volatile("s_waitcnt vmcnt(0)" ::: "memory");
        __syncthreads();

        // ---- main K loop: 32 x (4 ds_read + 8 MFMA), chunked staging ----
#pragma unroll
        for (int k0 = 0; k0 < 32; ++k0) {
            if ((k0 & 7) == 0 && k0 > 0) {
                asm volatile("s_waitcnt vmcnt(0)" ::: "memory");
                __syncthreads();
            }
            if ((k0 & 7) == 0 && k0 < 24) {
                const int nc = (k0 >> 3) + 1;
                const u16* gsrc = wswblk + (size_t)nc * 16384;
#pragma unroll
                for (int rr = 0; rr < 8; ++rr) {
                    const int ub = wave * 4096 + rr * 512;
                    async_copy16(gsrc + ub + lane * 8, &wlds[nc & 1][ub]);
                }
            }
            if (k0 + 5 < 32) {
                const int s = (k0 + 5) % 6;
                br[s][0] = *(const s16x8*)(hrow0 + (k0 + 5) * 32);
                br[s][1] = *(const s16x8*)(hrow1 + (k0 + 5) * 32);
            }
            const int cur = k0 % 6;
            const int buf = (k0 >> 3) & 1;
#pragma unroll
            for (int g = 0; g < 4; ++g) {
                const int f = ((g * 8 + (k0 & 7)) * 64 + lane) * 8;   // shorts
                s16x8 a = *(const s16x8*)&wlds[buf][f];
                acc[g][0] = __builtin_amdgcn_mfma_f32_16x16x32_bf16(a, br[cur][0], acc[g][0], 0, 0, 0);
                acc[g][1] = __builtin_amdgcn_mfma_f32_16x16x32_bf16(a, br[cur][1], acc[g][1], 0, 0, 0);
            }
        }

        // ---- epilogue: ALU + coherent h store. C/D: col=lane&15, row=quad*4+reg
#pragma unroll
        for (int nt = 0; nt < 2; ++nt) {
            const int c = c0 + nt * 16 + lm;
            const int rb = r0 + quad * 4;
            f32x4 cnew;
            s16x4 hnew;
#pragma unroll
            for (int reg = 0; reg < 4; ++reg) {
                float pg = clamp30(acc[0][nt][reg] + qv[nt][0][reg]);
                float pi = clamp30(acc[1][nt][reg] + qv[nt][1][reg]);
                float pf = clamp30(acc[2][nt][reg] + qv[nt][2][reg]);
                float po = clamp30(acc[3][nt][reg] + qv[nt][3][reg]);
                float gg = tanh_fast(pg);
                float ii = sigmoid_fast(pi);
                float ff = sigmoid_fast(pf);
                float oo = sigmoid_fast(po);
                float c2 = gg * ii + creg[nt][reg] * ff;
                c2 = fminf(fmaxf(c2, -200.0f), 200.0f);
                cnew[reg] = c2;
                hnew[reg] = (short)f2b(tanh_fast(c2) * oo);
            }
            creg[nt] = cnew;
            i32x2 hv;
            __builtin_memcpy(&hv, &hnew, 8);
            short* hp = hout + (size_t)c * kH + rb;
            // write-through to L3: device-visible once vmcnt drains.
            asm volatile("global_store_dwordx2 %0, %1, off sc0 sc1"
                         :: "v"(hp), "v"(hv) : "memory");
        }

        if (t < kT - 1) {
            // ---- grid barrier ----
            asm volatile("s_waitcnt vmcnt(0)" ::: "memory");  // own h stores done
            __syncthreads();                                  // whole block done
            if (tid < 64) {
                if (tid == 0) {
                    int* fp = flags + blk;
                    int fv = t + 1;
                    asm volatile("global_store_dword %0, %1, off sc0 sc1\n\t"
                                 "s_waitcnt vmcnt(0)"
                                 :: "v"(fp), "v"(fv) : "memory");
                }
                const int* fp = flags + lane * 8;   // 64 lanes x 8 = all 512
                for (;;) {
                    i32x4 fa, fb;
                    asm volatile(
                        "global_load_dwordx4 %0, %2, off sc0 sc1\n\t"
                        "global_load_dwordx4 %1, %2, off offset:16 sc0 sc1\n\t"
                        "s_waitcnt vmcnt(0)"
                        : "=&v"(fa), "=&v"(fb) : "v"(fp) : "memory");
                    int ok = (fa.x > t) & (fa.y > t) & (fa.z > t) & (fa.w > t) &
                             (fb.x > t) & (fb.y > t) & (fb.z > t) & (fb.w > t);
                    if (__all(ok)) break;
                    __builtin_amdgcn_s_sleep(1);
                }
                // ONE acquire per block per step: invalidates this CU's L1 +
                // this XCD's L2 so next step's cached h reads are fresh.
                __builtin_amdgcn_fence(__ATOMIC_ACQUIRE, "agent");
            }
            __syncthreads();
        }
    }
}

// ---------------------------------------------------------------------------
// Logits: p[b][cls] = h[b,:] . W_ph[cls,:] + b_p[cls]; log_softmax over 10.
// ---------------------------------------------------------------------------
__global__ __launch_bounds__(256) void logits_kernel(
    const u16* __restrict__ hT, const float* __restrict__ Wph,
    const float* __restrict__ bp, float* __restrict__ out)
{
    const int wave = threadIdx.x >> 6;
    const int lane = threadIdx.x & 63;
    const int b = blockIdx.x * 4 + wave;

    const u16* hp = hT + (size_t)b * kH + lane * 16;
    float hf[16];
#pragma unroll
    for (int j = 0; j < 16; ++j) hf[j] = b2f(hp[j]);

    float p[kC];
#pragma unroll
    for (int cls = 0; cls < kC; ++cls) {
        const float* wp = Wph + (size_t)cls * kH + lane * 16;
        float s = 0.f;
#pragma unroll
        for (int j = 0; j < 16; ++j) s += hf[j] * wp[j];
#pragma unroll
        for (int off = 1; off < 64; off <<= 1) s += __shfl_xor(s, off, 64);
        p[cls] = fminf(fmaxf(s + bp[cls], -1.0e4f), 1.0e4f);
    }

    float m = p[0];
#pragma unroll
    for (int cls = 1; cls < kC; ++cls) m = fmaxf(m, p[cls]);
    float se = 0.f;
#pragma unroll
    for (int cls = 0; cls < kC; ++cls) se += __expf(p[cls] - m);
    float l = m + __logf(se);

    if (lane < kC) {
        float myp = p[0];
#pragma unroll
        for (int cls = 1; cls < kC; ++cls)
            if (lane == cls) myp = p[cls];
        out[(size_t)b * kC + lane] = myp - l;
    }
}

// ---------------------------------------------------------------------------
extern "C" void kernel_launch(void* const* d_in, const int* in_sizes, int n_in,
                              void* d_out, int out_size, void* d_ws, size_t ws_size,
                              hipStream_t stream)
{
    const int*   x   = (const int*)  d_in[0];
    const float* emb = (const float*)d_in[1];
    const float* Wgx = (const float*)d_in[2];
    const float* Wgh = (const float*)d_in[3];
    const float* bg  = (const float*)d_in[4];
    const float* Wix = (const float*)d_in[5];
    const float* Wih = (const float*)d_in[6];
    const float* bi  = (const float*)d_in[7];
    const float* Wfx = (const float*)d_in[8];
    const float* Wfh = (const float*)d_in[9];
    const float* bf_ = (const float*)d_in[10];
    const float* Wox = (const float*)d_in[11];
    const float* Woh = (const float*)d_in[12];
    const float* bo  = (const float*)d_in[13];
    const float* Wph = (const float*)d_in[14];
    const float* bp  = (const float*)d_in[15];
    const float* h0  = (const float*)d_in[16];
    const float* c0  = (const float*)d_in[17];

    char* ws = (char*)d_ws;
    float* Qp  = (float*)ws;                              // 64 KB
    u16*   hA  = (u16*)(ws + (64 << 10));                 // 2 MB
    u16*   hB  = hA + (size_t)kB * kH;                    // 2 MB
    float* cT  = (float*)(hB + (size_t)kB * kH);          // 4 MB
    u16*   wsw = (u16*)(cT + (size_t)kB * kH);            // 8 MB
    int*   flags = (int*)(wsw + (size_t)64 * 65536);      // 2 KB (total ~16.07 MB)

    prep_weights<<<dim3(2048), dim3(256), 0, stream>>>(Wgh, Wih, Wfh, Woh, wsw);
    prep_hc<<<dim3(kB / 32, kH / 32), dim3(32, 32), 0, stream>>>(h0, c0, hA, cT);
    prep_q<<<dim3(16), dim3(256), 0, stream>>>(Wgx, Wix, Wfx, Wox, bg, bi, bf_, bo,
                                               emb, Qp, flags);

    lstm_persist<<<dim3(512), dim3(256), 0, stream>>>(
        wsw, Qp, x, (short*)hA, (short*)hB, cT, flags);

    // 127 steps: t=126 (even) wrote hB.
    logits_kernel<<<dim3(kB / 4), dim3(256), 0, stream>>>(hB, Wph, bp, (float*)d_out);
}

// Round 2
// 2760.269 us; speedup vs baseline: 1.3439x; 1.3439x over previous
//
#include <hip/hip_runtime.h>

// LSTM: H=1024, B=1024, S=128 (T=127 steps), E=6, V=3, C=10.
// R14: persistent kernel with LDS-RESIDENT weights.
// R13 post-mortem: per-step agent-acquire fence invalidated L2, so the
// 64 MB/step weight re-staging (8x duplicated) came from memory every step
// (FETCH_SIZE showed 8.3 MB/step = the weight array) and the K-loop's
// chunk drains stalled on cold fetches. Fix: retile to 256 blocks x 512 thr
// (1 block/CU), 128 KB static LDS holds the block's full weight slice
// (16 rows x 4 gates x K=1024 bf16), staged ONCE at t=0. Per-step K-loop is
// pure ds_read+MFMA: no staging, no mid-loop barriers, fence-immune.
//  - c state in registers for all 127 steps.
//  - h stores: global_store_dwordx2 sc0 sc1 (write-through, device-visible
//    after vmcnt(0)); h reads plain/cached + ONE acquire(agent) fence per
//    block per step after the grid barrier (R13-proven scheme).
//  - grid barrier: 256 per-block flags (monotonic step counter) sc0 sc1;
//    wave 0 polls all 256 with a single dwordx4 sc0 sc1 per lane.
constexpr int kH = 1024;
constexpr int kB = 1024;
constexpr int kS = 128;
constexpr int kT = 127;
constexpr int kE = 6;
constexpr int kV = 3;
constexpr int kC = 10;

typedef short s16x8 __attribute__((ext_vector_type(8)));
typedef short s16x4 __attribute__((ext_vector_type(4)));
typedef float f32x4 __attribute__((ext_vector_type(4)));
typedef int   i32x2 __attribute__((ext_vector_type(2)));
typedef int   i32x4 __attribute__((ext_vector_type(4)));
typedef unsigned short u16;

__device__ __forceinline__ float b2f(u16 u) {
    return __uint_as_float(((unsigned)u) << 16);
}
__device__ __forceinline__ u16 f2b(float f) {
    unsigned u = __float_as_uint(f);
    return (u16)((u + 0x7FFFu + ((u >> 16) & 1u)) >> 16);   // RNE
}
__device__ __forceinline__ float sigmoid_fast(float x) {
    return 1.0f / (1.0f + __expf(-x));
}
__device__ __forceinline__ float tanh_fast(float x) {
    return 2.0f / (1.0f + __expf(-2.0f * x)) - 1.0f;
}
__device__ __forceinline__ float clamp30(float x) {
    return fminf(fmaxf(x, -30.0f), 30.0f);
}

__device__ __forceinline__ void async_copy16(const u16* g, u16* l) {
    __builtin_amdgcn_global_load_lds(
        (const __attribute__((address_space(1))) void*)g,
        (__attribute__((address_space(3))) void*)l, 16, 0, 0);
}

// ---------------------------------------------------------------------------
// Prep 1: weights fp32 -> bf16, frag-major (identical to R8/R12/R13):
//   grp = (((by*4 + kc)*4 + g)*8 + k0)*64 + lane
//   wsw[grp*8 + j] = W_g[by*16 + (lane&15)][kc*256 + k0*32 + (lane>>4)*8 + j]
// ---------------------------------------------------------------------------
__global__ __launch_bounds__(256) void prep_weights(
    const float* __restrict__ Wgh, const float* __restrict__ Wih,
    const float* __restrict__ Wfh, const float* __restrict__ Woh,
    u16* __restrict__ wsw)
{
    unsigned grp = blockIdx.x * 256 + threadIdx.x;    // 0 .. 2^19-1
    const int lane = grp & 63;
    const int lm   = lane & 15;
    const int quad = lane >> 4;
    const int k0   = (grp >> 6) & 7;
    const int g    = (grp >> 9) & 3;
    const int kc   = (grp >> 11) & 3;
    const int by   = grp >> 13;                       // 0..63
    const float* src = (g == 0) ? Wgh : (g == 1) ? Wih : (g == 2) ? Wfh : Woh;
    const int row = by * 16 + lm;
    const int k   = kc * 256 + k0 * 32 + quad * 8;
    f32x4 v0 = *(const f32x4*)(src + (size_t)row * kH + k);
    f32x4 v1 = *(const f32x4*)(src + (size_t)row * kH + k + 4);
    s16x8 o;
#pragma unroll
    for (int j = 0; j < 4; ++j) o[j] = (short)f2b(v0[j]);
#pragma unroll
    for (int j = 0; j < 4; ++j) o[4 + j] = (short)f2b(v1[j]);
    *(s16x8*)(wsw + (size_t)grp * 8) = o;
}

// ---------------------------------------------------------------------------
// Prep 2: transpose h0 (H,B) fp32 -> hA (B,H) bf16; c0 (H,B) -> cT (B,H) fp32.
// ---------------------------------------------------------------------------
__global__ __launch_bounds__(1024) void prep_hc(
    const float* __restrict__ h0, const float* __restrict__ c0,
    u16* __restrict__ hA, float* __restrict__ cT)
{
    __shared__ float th[32][33];
    __shared__ float tc[32][33];
    int b = blockIdx.x * 32 + threadIdx.x;
    int h = blockIdx.y * 32 + threadIdx.y;
    th[threadIdx.y][threadIdx.x] = h0[(size_t)h * kB + b];
    tc[threadIdx.y][threadIdx.x] = c0[(size_t)h * kB + b];
    __syncthreads();
    int ob = blockIdx.x * 32 + threadIdx.y;
    int oh = blockIdx.y * 32 + threadIdx.x;
    hA[(size_t)ob * kH + oh] = f2b(th[threadIdx.x][threadIdx.y]);
    cT[(size_t)ob * kH + oh] = tc[threadIdx.x][threadIdx.y];
}

// ---------------------------------------------------------------------------
// Prep 3: gate constants repacked as f32x4 (unchanged), plus zeroing the
// barrier flags (re-zeroed every graph replay, stream-ordered before the
// persistent kernel).
// ---------------------------------------------------------------------------
__global__ __launch_bounds__(256) void prep_q(
    const float* __restrict__ Wgx, const float* __restrict__ Wix,
    const float* __restrict__ Wfx, const float* __restrict__ Wox,
    const float* __restrict__ bg,  const float* __restrict__ bi,
    const float* __restrict__ bf_, const float* __restrict__ bo,
    const float* __restrict__ emb, float* __restrict__ Qp,
    int* __restrict__ flags)
{
    int tid = blockIdx.x * blockDim.x + threadIdx.x;   // 0..4095
    if (tid < 512) flags[tid] = 0;
    if (tid >= 4096) return;
    int g   = tid >> 10;
    int hr4 = (tid & 1023) >> 2;
    int v   = tid & 3;
    const float* Wx = (g == 0) ? Wgx : (g == 1) ? Wix : (g == 2) ? Wfx : Wox;
    const float* bb = (g == 0) ? bg  : (g == 1) ? bi  : (g == 2) ? bf_ : bo;
    f32x4 o;
#pragma unroll
    for (int reg = 0; reg < 4; ++reg) {
        int row = hr4 * 4 + reg;
        float s = bb[row];
        if (v < kV) {
#pragma unroll
            for (int e = 0; e < kE; ++e) s += Wx[row * kE + e] * emb[v * kE + e];
        }
        o[reg] = s;
    }
    *(f32x4*)(Qp + (size_t)tid * 4) = o;
}

// ---------------------------------------------------------------------------
// Persistent LSTM, LDS-resident weights: all 127 timesteps in one launch.
// Grid 256 x 512 thr (1 block/CU, 8 waves). Block tile: 16 h-rows x 4 gates
// x 256 cols; wave w: cols [bx*256 + 32w, +32) (nt=2).
// XCD swizzle: xcd=blk&7, slot=blk>>3 (0..31), by=xcd*8+(slot&7) (0..63),
// bx=slot>>3 (0..3). Per XCD: all 4 col-tiles -> h-reads L2-resident.
// Weights: full 128 KB by-slice staged to LDS once at t=0; K-loop has no
// global staging and no barriers.
// b-operand: depth-6 free-running register ring from global h (cached loads;
// safe because the acquire fence precedes every step's h reads).
// ---------------------------------------------------------------------------
__global__ __launch_bounds__(512, 2) void lstm_persist(
    const u16* __restrict__ wsw, const float* __restrict__ Qp,
    const int* __restrict__ x,
    short* __restrict__ hA, short* __restrict__ hB,
    const float* __restrict__ cT, int* __restrict__ flags)
{
    __shared__ u16 wlds[65536];   // 128 KB, resident all 127 steps

    const int tid  = threadIdx.x;
    const int lane = tid & 63;
    const int wave = tid >> 6;              // 0..7
    const int lm   = lane & 15;
    const int quad = lane >> 4;
    const int blk  = blockIdx.x;            // 0..255
    const int xcd  = blk & 7;
    const int slot = blk >> 3;              // 0..31
    const int by   = xcd * 8 + (slot & 7);  // 0..63
    const int bx   = slot >> 3;             // 0..3
    const int r0 = by * 16;
    const int c0 = bx * 256 + wave * 32;

    const u16* wswblk = wsw + (size_t)by * 65536;

    // ---- stage the whole weight slice once (async, 128 KB) ----
#pragma unroll
    for (int rr = 0; rr < 16; ++rr) {
        const int ub = wave * 8192 + rr * 512;   // shorts
        async_copy16(wswblk + ub + lane * 8, &wlds[ub]);
    }

    // ---- persistent c state: loaded once, lives in registers 127 steps ----
    f32x4 creg[2];
#pragma unroll
    for (int nt = 0; nt < 2; ++nt)
        creg[nt] = *(const f32x4*)(cT +
            (size_t)(c0 + nt * 16 + lm) * kH + r0 + quad * 4);

    const int* xp0 = x + (size_t)(c0 + lm) * kS;
    const int* xp1 = x + (size_t)(c0 + 16 + lm) * kS;
    const int koff = quad * 8;

    asm volatile("s_waitcnt vmcnt(0)" ::: "memory");
    __syncthreads();   // weights resident from here on

#pragma unroll 1
    for (int t = 0; t < kT; ++t) {
        const short* hin  = (t & 1) ? hB : hA;
        short*       hout = (t & 1) ? hA : hB;

        // ---- per-step loads: x -> vv -> Qp vectors (issued early; x and Qp
        // are immutable, so stale cache hits are fine) ----
        int vv[2];
        {
            int v0 = xp0[t]; vv[0] = (v0 < 0) ? 0 : (v0 > kV - 1) ? (kV - 1) : v0;
            int v1 = xp1[t]; vv[1] = (v1 < 0) ? 0 : (v1 > kV - 1) ? (kV - 1) : v1;
        }
        f32x4 qv[2][4];
#pragma unroll
        for (int nt = 0; nt < 2; ++nt)
#pragma unroll
            for (int g = 0; g < 4; ++g)
                qv[nt][g] = *(const f32x4*)(Qp +
                    (size_t)(((g * 256 + by * 4 + quad) * 4 + vv[nt]) * 4));

        // ---- b-ring prologue: slots 0..4 ----
        const short* hrow0 = hin + (size_t)(c0 + lm) * kH + koff;
        const short* hrow1 = hin + (size_t)(c0 + 16 + lm) * kH + koff;
        s16x8 br[6][2];
#pragma unroll
        for (int s = 0; s < 5; ++s) {
            br[s][0] = *(const s16x8*)(hrow0 + s * 32);
            br[s][1] = *(const s16x8*)(hrow1 + s * 32);
        }

        f32x4 acc[4][2];
        const f32x4 zero = {0.f, 0.f, 0.f, 0.f};
#pragma unroll
        for (int g = 0; g < 4; ++g)
#pragma unroll
            for (int n = 0; n < 2; ++n) acc[g][n] = zero;

        // ---- main K loop: 32 x (4 ds_read_b128 + 8 MFMA), no staging,
        //      no barriers (LDS is read-only) ----
#pragma unroll
        for (int k0 = 0; k0 < 32; ++k0) {
            if (k0 + 5 < 32) {
                const int s = (k0 + 5) % 6;
                br[s][0] = *(const s16x8*)(hrow0 + (k0 + 5) * 32);
                br[s][1] = *(const s16x8*)(hrow1 + (k0 + 5) * 32);
            }
            const int cur = k0 % 6;
            const int cb = (k0 >> 3) * 16384;         // K-chunk base (shorts)
#pragma unroll
            for (int g = 0; g < 4; ++g) {
                const int f = cb + ((g * 8 + (k0 & 7)) * 64 + lane) * 8;
                s16x8 a = *(const s16x8*)&wlds[f];
                acc[g][0] = __builtin_amdgcn_mfma_f32_16x16x32_bf16(a, br[cur][0], acc[g][0], 0, 0, 0);
                acc[g][1] = __builtin_amdgcn_mfma_f32_16x16x32_bf16(a, br[cur][1], acc[g][1], 0, 0, 0);
            }
        }

        // ---- epilogue: ALU + coherent h store. C/D: col=lane&15, row=quad*4+reg
#pragma unroll
        for (int nt = 0; nt < 2; ++nt) {
            const int c = c0 + nt * 16 + lm;
            const int rb = r0 + quad * 4;
            f32x4 cnew;
            s16x4 hnew;
#pragma unroll
            for (int reg = 0; reg < 4; ++reg) {
                float pg = clamp30(acc[0][nt][reg] + qv[nt][0][reg]);
                float pi = clamp30(acc[1][nt][reg] + qv[nt][1][reg]);
                float pf = clamp30(acc[2][nt][reg] + qv[nt][2][reg]);
                float po = clamp30(acc[3][nt][reg] + qv[nt][3][reg]);
                float gg = tanh_fast(pg);
                float ii = sigmoid_fast(pi);
                float ff = sigmoid_fast(pf);
                float oo = sigmoid_fast(po);
                float c2 = gg * ii + creg[nt][reg] * ff;
                c2 = fminf(fmaxf(c2, -200.0f), 200.0f);
                cnew[reg] = c2;
                hnew[reg] = (short)f2b(tanh_fast(c2) * oo);
            }
            creg[nt] = cnew;
            i32x2 hv;
            __builtin_memcpy(&hv, &hnew, 8);
            short* hp = hout + (size_t)c * kH + rb;
            // write-through to L3: device-visible once vmcnt drains.
            asm volatile("global_store_dwordx2 %0, %1, off sc0 sc1"
                         :: "v"(hp), "v"(hv) : "memory");
        }

        if (t < kT - 1) {
            // ---- grid barrier across 256 blocks ----
            asm volatile("s_waitcnt vmcnt(0)" ::: "memory");  // own h stores done
            __syncthreads();                                  // whole block done
            if (tid < 64) {
                if (tid == 0) {
                    int* fp = flags + blk;
                    int fv = t + 1;
                    asm volatile("global_store_dword %0, %1, off sc0 sc1\n\t"
                                 "s_waitcnt vmcnt(0)"
                                 :: "v"(fp), "v"(fv) : "memory");
                }
                const int* fp = flags + lane * 4;   // 64 lanes x 4 = all 256
                for (;;) {
                    i32x4 fa;
                    asm volatile(
                        "global_load_dwordx4 %0, %1, off sc0 sc1\n\t"
                        "s_waitcnt vmcnt(0)"
                        : "=&v"(fa) : "v"(fp) : "memory");
                    int ok = (fa.x > t) & (fa.y > t) & (fa.z > t) & (fa.w > t);
                    if (__all(ok)) break;
                    __builtin_amdgcn_s_sleep(1);
                }
                // ONE acquire per block per step: invalidates this CU's L1 +
                // this XCD's L2 so next step's cached h reads are fresh.
                // Weights are in LDS -> immune to the invalidate.
                __builtin_amdgcn_fence(__ATOMIC_ACQUIRE, "agent");
            }
            __syncthreads();
        }
    }
}

// ---------------------------------------------------------------------------
// Logits: p[b][cls] = h[b,:] . W_ph[cls,:] + b_p[cls]; log_softmax over 10.
// ---------------------------------------------------------------------------
__global__ __launch_bounds__(256) void logits_kernel(
    const u16* __restrict__ hT, const float* __restrict__ Wph,
    const float* __restrict__ bp, float* __restrict__ out)
{
    const int wave = threadIdx.x >> 6;
    const int lane = threadIdx.x & 63;
    const int b = blockIdx.x * 4 + wave;

    const u16* hp = hT + (size_t)b * kH + lane * 16;
    float hf[16];
#pragma unroll
    for (int j = 0; j < 16; ++j) hf[j] = b2f(hp[j]);

    float p[kC];
#pragma unroll
    for (int cls = 0; cls < kC; ++cls) {
        const float* wp = Wph + (size_t)cls * kH + lane * 16;
        float s = 0.f;
#pragma unroll
        for (int j = 0; j < 16; ++j) s += hf[j] * wp[j];
#pragma unroll
        for (int off = 1; off < 64; off <<= 1) s += __shfl_xor(s, off, 64);
        p[cls] = fminf(fmaxf(s + bp[cls], -1.0e4f), 1.0e4f);
    }

    float m = p[0];
#pragma unroll
    for (int cls = 1; cls < kC; ++cls) m = fmaxf(m, p[cls]);
    float se = 0.f;
#pragma unroll
    for (int cls = 0; cls < kC; ++cls) se += __expf(p[cls] - m);
    float l = m + __logf(se);

    if (lane < kC) {
        float myp = p[0];
#pragma unroll
        for (int cls = 1; cls < kC; ++cls)
            if (lane == cls) myp = p[cls];
        out[(size_t)b * kC + lane] = myp - l;
    }
}

// ---------------------------------------------------------------------------
extern "C" void kernel_launch(void* const* d_in, const int* in_sizes, int n_in,
                              void* d_out, int out_size, void* d_ws, size_t ws_size,
                              hipStream_t stream)
{
    const int*   x   = (const int*)  d_in[0];
    const float* emb = (const float*)d_in[1];
    const float* Wgx = (const float*)d_in[2];
    const float* Wgh = (const float*)d_in[3];
    const float* bg  = (const float*)d_in[4];
    const float* Wix = (const float*)d_in[5];
    const float* Wih = (const float*)d_in[6];
    const float* bi  = (const float*)d_in[7];
    const float* Wfx = (const float*)d_in[8];
    const float* Wfh = (const float*)d_in[9];
    const float* bf_ = (const float*)d_in[10];
    const float* Wox = (const float*)d_in[11];
    const float* Woh = (const float*)d_in[12];
    const float* bo  = (const float*)d_in[13];
    const float* Wph = (const float*)d_in[14];
    const float* bp  = (const float*)d_in[15];
    const float* h0  = (const float*)d_in[16];
    const float* c0  = (const float*)d_in[17];

    char* ws = (char*)d_ws;
    float* Qp  = (float*)ws;                              // 64 KB
    u16*   hA  = (u16*)(ws + (64 << 10));                 // 2 MB
    u16*   hB  = hA + (size_t)kB * kH;                    // 2 MB
    float* cT  = (float*)(hB + (size_t)kB * kH);          // 4 MB
    u16*   wsw = (u16*)(cT + (size_t)kB * kH);            // 8 MB
    int*   flags = (int*)(wsw + (size_t)64 * 65536);      // 2 KB (total ~16.07 MB)

    prep_weights<<<dim3(2048), dim3(256), 0, stream>>>(Wgh, Wih, Wfh, Woh, wsw);
    prep_hc<<<dim3(kB / 32, kH / 32), dim3(32, 32), 0, stream>>>(h0, c0, hA, cT);
    prep_q<<<dim3(16), dim3(256), 0, stream>>>(Wgx, Wix, Wfx, Wox, bg, bi, bf_, bo,
                                               emb, Qp, flags);

    lstm_persist<<<dim3(256), dim3(512), 0, stream>>>(
        wsw, Qp, x, (short*)hA, (short*)hB, cT, flags);

    // 127 steps: t=126 (even) wrote hB.
    logits_kernel<<<dim3(kB / 4), dim3(256), 0, stream>>>(hB, Wph, bp, (float*)d_out);
}

// Round 3
// 2522.810 us; speedup vs baseline: 1.4704x; 1.0941x over previous
//
#include <hip/hip_runtime.h>

// LSTM: H=1024, B=1024, S=128 (T=127 steps), E=6, V=3, C=10.
// R15: persistent + LDS-resident weights (R14) with coherence redesign:
//  - Runtime XCD identity: s_getreg(HW_REG_XCC_ID) + atomicAdd rank. Block
//    (xcc, rank) -> row-group q = (xcc&1)*32+rank (0..63), col-group
//    p = xcc>>1 (0..3). Columns are closed within an XCD PAIR: all h
//    exchange for a 256-col group stays in 2 XCDs; the 4 pairs run
//    independent 64-block barriers (was one 256-block barrier).
//  - ONE buffer_inv sc1 per XCD per step (rank-0 leader) instead of 32
//    per-block agent fences; non-leaders poll a release flag (sc0 sc1,
//    no L2 churn) and do a vL1-only buffer_inv. h reads stay plain/L2-
//    cached (L2 ~34 TB/s stays in the path).
//  - b-ring deepened to 12 slots / lookahead 10 (~20 loads in flight per
//    wave) to cover post-invalidate L3 first-touch latency.
//  - c state in registers all 127 steps; h stores sc0 sc1 write-through.
constexpr int kH = 1024;
constexpr int kB = 1024;
constexpr int kS = 128;
constexpr int kT = 127;
constexpr int kE = 6;
constexpr int kV = 3;
constexpr int kC = 10;

typedef short s16x8 __attribute__((ext_vector_type(8)));
typedef short s16x4 __attribute__((ext_vector_type(4)));
typedef float f32x4 __attribute__((ext_vector_type(4)));
typedef int   i32x2 __attribute__((ext_vector_type(2)));
typedef unsigned short u16;

__device__ __forceinline__ float b2f(u16 u) {
    return __uint_as_float(((unsigned)u) << 16);
}
__device__ __forceinline__ u16 f2b(float f) {
    unsigned u = __float_as_uint(f);
    return (u16)((u + 0x7FFFu + ((u >> 16) & 1u)) >> 16);   // RNE
}
__device__ __forceinline__ float sigmoid_fast(float x) {
    return 1.0f / (1.0f + __expf(-x));
}
__device__ __forceinline__ float tanh_fast(float x) {
    return 2.0f / (1.0f + __expf(-2.0f * x)) - 1.0f;
}
__device__ __forceinline__ float clamp30(float x) {
    return fminf(fmaxf(x, -30.0f), 30.0f);
}

__device__ __forceinline__ void async_copy16(const u16* g, u16* l) {
    __builtin_amdgcn_global_load_lds(
        (const __attribute__((address_space(1))) void*)g,
        (__attribute__((address_space(3))) void*)l, 16, 0, 0);
}

// ---------------------------------------------------------------------------
// Prep 1: weights fp32 -> bf16, frag-major (identical to R8..R14):
//   grp = (((by*4 + kc)*4 + g)*8 + k0)*64 + lane
//   wsw[grp*8 + j] = W_g[by*16 + (lane&15)][kc*256 + k0*32 + (lane>>4)*8 + j]
// ---------------------------------------------------------------------------
__global__ __launch_bounds__(256) void prep_weights(
    const float* __restrict__ Wgh, const float* __restrict__ Wih,
    const float* __restrict__ Wfh, const float* __restrict__ Woh,
    u16* __restrict__ wsw)
{
    unsigned grp = blockIdx.x * 256 + threadIdx.x;    // 0 .. 2^19-1
    const int lane = grp & 63;
    const int lm   = lane & 15;
    const int quad = lane >> 4;
    const int k0   = (grp >> 6) & 7;
    const int g    = (grp >> 9) & 3;
    const int kc   = (grp >> 11) & 3;
    const int by   = grp >> 13;                       // 0..63
    const float* src = (g == 0) ? Wgh : (g == 1) ? Wih : (g == 2) ? Wfh : Woh;
    const int row = by * 16 + lm;
    const int k   = kc * 256 + k0 * 32 + quad * 8;
    f32x4 v0 = *(const f32x4*)(src + (size_t)row * kH + k);
    f32x4 v1 = *(const f32x4*)(src + (size_t)row * kH + k + 4);
    s16x8 o;
#pragma unroll
    for (int j = 0; j < 4; ++j) o[j] = (short)f2b(v0[j]);
#pragma unroll
    for (int j = 0; j < 4; ++j) o[4 + j] = (short)f2b(v1[j]);
    *(s16x8*)(wsw + (size_t)grp * 8) = o;
}

// ---------------------------------------------------------------------------
// Prep 2: transpose h0 (H,B) fp32 -> hA (B,H) bf16; c0 (H,B) -> cT (B,H) fp32.
// ---------------------------------------------------------------------------
__global__ __launch_bounds__(1024) void prep_hc(
    const float* __restrict__ h0, const float* __restrict__ c0,
    u16* __restrict__ hA, float* __restrict__ cT)
{
    __shared__ float th[32][33];
    __shared__ float tc[32][33];
    int b = blockIdx.x * 32 + threadIdx.x;
    int h = blockIdx.y * 32 + threadIdx.y;
    th[threadIdx.y][threadIdx.x] = h0[(size_t)h * kB + b];
    tc[threadIdx.y][threadIdx.x] = c0[(size_t)h * kB + b];
    __syncthreads();
    int ob = blockIdx.x * 32 + threadIdx.y;
    int oh = blockIdx.y * 32 + threadIdx.x;
    hA[(size_t)ob * kH + oh] = f2b(th[threadIdx.x][threadIdx.y]);
    cT[(size_t)ob * kH + oh] = tc[threadIdx.x][threadIdx.y];
}

// ---------------------------------------------------------------------------
// Prep 3: gate constants repacked as f32x4 (unchanged), plus zeroing the
// control block (flags[256] @0, release[8] @256, xccCnt[8] @264) every
// graph replay, stream-ordered before the persistent kernel.
// ---------------------------------------------------------------------------
__global__ __launch_bounds__(256) void prep_q(
    const float* __restrict__ Wgx, const float* __restrict__ Wix,
    const float* __restrict__ Wfx, const float* __restrict__ Wox,
    const float* __restrict__ bg,  const float* __restrict__ bi,
    const float* __restrict__ bf_, const float* __restrict__ bo,
    const float* __restrict__ emb, float* __restrict__ Qp,
    int* __restrict__ ctrl)
{
    int tid = blockIdx.x * blockDim.x + threadIdx.x;   // 0..4095
    if (tid < 512) ctrl[tid] = 0;
    if (tid >= 4096) return;
    int g   = tid >> 10;
    int hr4 = (tid & 1023) >> 2;
    int v   = tid & 3;
    const float* Wx = (g == 0) ? Wgx : (g == 1) ? Wix : (g == 2) ? Wfx : Wox;
    const float* bb = (g == 0) ? bg  : (g == 1) ? bi  : (g == 2) ? bf_ : bo;
    f32x4 o;
#pragma unroll
    for (int reg = 0; reg < 4; ++reg) {
        int row = hr4 * 4 + reg;
        float s = bb[row];
        if (v < kV) {
#pragma unroll
            for (int e = 0; e < kE; ++e) s += Wx[row * kE + e] * emb[v * kE + e];
        }
        o[reg] = s;
    }
    *(f32x4*)(Qp + (size_t)tid * 4) = o;
}

// ---------------------------------------------------------------------------
// Persistent LSTM: 256 blocks x 512 thr (1 block/CU, 8 waves), weights
// LDS-resident. Block identity from HW: xcc = XCC_ID, rank = arrival order
// within XCD. q = (xcc&1)*32 + rank (row-group, 16 rows x 4 gates),
// p = xcc>>1 (col-group, 256 cols). Wave w: cols [p*256+32w, +32) (nt=2).
// Per-step sync per XCD pair: 64 flags; rank-0 leader per XCD does the
// single buffer_inv sc1 + release.
// ---------------------------------------------------------------------------
__global__ __launch_bounds__(512, 2) void lstm_persist(
    const u16* __restrict__ wsw, const float* __restrict__ Qp,
    const int* __restrict__ x,
    short* __restrict__ hA, short* __restrict__ hB,
    const float* __restrict__ cT, int* __restrict__ ctrl)
{
    __shared__ u16 wlds[65536];   // 128 KB, resident all 127 steps
    __shared__ int sh_ids[2];

    const int tid  = threadIdx.x;
    const int lane = tid & 63;
    const int wave = tid >> 6;              // 0..7
    const int lm   = lane & 15;
    const int quad = lane >> 4;

    // ---- runtime identity: XCD id + arrival rank within XCD ----
    if (tid == 0) {
        unsigned xccr;
        asm volatile("s_getreg_b32 %0, hwreg(HW_REG_XCC_ID)" : "=s"(xccr));
        int rank = atomicAdd(ctrl + 264 + (xccr & 7), 1);
        sh_ids[0] = (int)(xccr & 7);
        sh_ids[1] = rank;
    }
    __syncthreads();
    const int xcc  = sh_ids[0];
    const int rank = sh_ids[1];             // 0..31 within XCD
    const int p    = xcc >> 1;              // col-group 0..3 (XCD pair)
    const int q    = (xcc & 1) * 32 + rank; // row-group 0..63 within pair
    const bool leader = (rank == 0);
    const int r0 = q * 16;
    const int c0 = p * 256 + wave * 32;

    int* flags   = ctrl;            // [p*64 + q], monotonic step counters
    int* release = ctrl + 256;      // [xcc]

    const u16* wswblk = wsw + (size_t)q * 65536;

    // ---- stage the whole weight slice once (async, 128 KB) ----
#pragma unroll
    for (int rr = 0; rr < 16; ++rr) {
        const int ub = wave * 8192 + rr * 512;   // shorts
        async_copy16(wswblk + ub + lane * 8, &wlds[ub]);
    }

    // ---- persistent c state: loaded once, lives in registers 127 steps ----
    f32x4 creg[2];
#pragma unroll
    for (int nt = 0; nt < 2; ++nt)
        creg[nt] = *(const f32x4*)(cT +
            (size_t)(c0 + nt * 16 + lm) * kH + r0 + quad * 4);

    const int* xp0 = x + (size_t)(c0 + lm) * kS;
    const int* xp1 = x + (size_t)(c0 + 16 + lm) * kS;
    const int koff = quad * 8;

    asm volatile("s_waitcnt vmcnt(0)" ::: "memory");
    __syncthreads();   // weights resident from here on

#pragma unroll 1
    for (int t = 0; t < kT; ++t) {
        const short* hin  = (t & 1) ? hB : hA;
        short*       hout = (t & 1) ? hA : hB;

        // ---- b-ring prologue: slots 0..9 (12-slot ring, lookahead 10) ----
        const short* hrow0 = hin + (size_t)(c0 + lm) * kH + koff;
        const short* hrow1 = hin + (size_t)(c0 + 16 + lm) * kH + koff;
        s16x8 br[12][2];
#pragma unroll
        for (int s = 0; s < 10; ++s) {
            br[s][0] = *(const s16x8*)(hrow0 + s * 32);
            br[s][1] = *(const s16x8*)(hrow1 + s * 32);
        }

        // ---- per-step loads: x -> vv -> Qp vectors ----
        int vv[2];
        {
            int v0 = xp0[t]; vv[0] = (v0 < 0) ? 0 : (v0 > kV - 1) ? (kV - 1) : v0;
            int v1 = xp1[t]; vv[1] = (v1 < 0) ? 0 : (v1 > kV - 1) ? (kV - 1) : v1;
        }
        f32x4 qv[2][4];
#pragma unroll
        for (int nt = 0; nt < 2; ++nt)
#pragma unroll
            for (int g = 0; g < 4; ++g)
                qv[nt][g] = *(const f32x4*)(Qp +
                    (size_t)(((g * 256 + q * 4 + quad) * 4 + vv[nt]) * 4));

        f32x4 acc[4][2];
        const f32x4 zero = {0.f, 0.f, 0.f, 0.f};
#pragma unroll
        for (int g = 0; g < 4; ++g)
#pragma unroll
            for (int n = 0; n < 2; ++n) acc[g][n] = zero;

        // ---- main K loop: 32 x (4 ds_read_b128 + 8 MFMA), ring loads ----
#pragma unroll
        for (int k0 = 0; k0 < 32; ++k0) {
            if (k0 + 10 < 32) {
                const int s = (k0 + 10) % 12;
                br[s][0] = *(const s16x8*)(hrow0 + (k0 + 10) * 32);
                br[s][1] = *(const s16x8*)(hrow1 + (k0 + 10) * 32);
            }
            const int cur = k0 % 12;
            const int cb = (k0 >> 3) * 16384;         // K-chunk base (shorts)
#pragma unroll
            for (int g = 0; g < 4; ++g) {
                const int f = cb + ((g * 8 + (k0 & 7)) * 64 + lane) * 8;
                s16x8 a = *(const s16x8*)&wlds[f];
                acc[g][0] = __builtin_amdgcn_mfma_f32_16x16x32_bf16(a, br[cur][0], acc[g][0], 0, 0, 0);
                acc[g][1] = __builtin_amdgcn_mfma_f32_16x16x32_bf16(a, br[cur][1], acc[g][1], 0, 0, 0);
            }
        }

        // ---- epilogue: ALU + coherent h store. C/D: col=lane&15, row=quad*4+reg
#pragma unroll
        for (int nt = 0; nt < 2; ++nt) {
            const int c = c0 + nt * 16 + lm;
            const int rb = r0 + quad * 4;
            f32x4 cnew;
            s16x4 hnew;
#pragma unroll
            for (int reg = 0; reg < 4; ++reg) {
                float pg = clamp30(acc[0][nt][reg] + qv[nt][0][reg]);
                float pi = clamp30(acc[1][nt][reg] + qv[nt][1][reg]);
                float pf = clamp30(acc[2][nt][reg] + qv[nt][2][reg]);
                float po = clamp30(acc[3][nt][reg] + qv[nt][3][reg]);
                float gg = tanh_fast(pg);
                float ii = sigmoid_fast(pi);
                float ff = sigmoid_fast(pf);
                float oo = sigmoid_fast(po);
                float c2 = gg * ii + creg[nt][reg] * ff;
                c2 = fminf(fmaxf(c2, -200.0f), 200.0f);
                cnew[reg] = c2;
                hnew[reg] = (short)f2b(tanh_fast(c2) * oo);
            }
            creg[nt] = cnew;
            i32x2 hv;
            __builtin_memcpy(&hv, &hnew, 8);
            short* hp = hout + (size_t)c * kH + rb;
            // write-through to L3: device-visible once vmcnt drains.
            asm volatile("global_store_dwordx2 %0, %1, off sc0 sc1"
                         :: "v"(hp), "v"(hv) : "memory");
        }

        if (t < kT - 1) {
            // ---- pair-local barrier + single L2 inv per XCD ----
            asm volatile("s_waitcnt vmcnt(0)" ::: "memory");  // h stores done
            __syncthreads();                                  // block done
            if (tid == 0) {
                int* fp = flags + p * 64 + q;
                int fv = t + 1;
                asm volatile("global_store_dword %0, %1, off sc0 sc1\n\t"
                             "s_waitcnt vmcnt(0)"
                             :: "v"(fp), "v"(fv) : "memory");
            }
            if (leader && tid < 64) {
                // leader wave0: wait for the pair's 64 flags
                const int* fp = flags + p * 64 + lane;
                for (;;) {
                    int fvv;
                    asm volatile(
                        "global_load_dword %0, %1, off sc0 sc1\n\t"
                        "s_waitcnt vmcnt(0)"
                        : "=v"(fvv) : "v"(fp) : "memory");
                    if (__all(fvv > t)) break;
                    __builtin_amdgcn_s_sleep(1);
                }
                if (lane == 0) {
                    // one L2 invalidate for this XCD, then release
                    asm volatile("buffer_inv sc1\n\t"
                                 "s_waitcnt vmcnt(0)" ::: "memory");
                    int* rp = release + xcc;
                    int rv = t + 1;
                    asm volatile("global_store_dword %0, %1, off sc0 sc1\n\t"
                                 "s_waitcnt vmcnt(0)"
                                 :: "v"(rp), "v"(rv) : "memory");
                }
            }
            if (tid < 64) {
                // everyone: wait own XCD's release, then vL1-only invalidate
                const int* rp = release + xcc;
                for (;;) {
                    int rvv;
                    asm volatile(
                        "global_load_dword %0, %1, off sc0 sc1\n\t"
                        "s_waitcnt vmcnt(0)"
                        : "=v"(rvv) : "v"(rp) : "memory");
                    if (__all(rvv > t)) break;
                    __builtin_amdgcn_s_sleep(1);
                }
                asm volatile("buffer_inv" ::: "memory");   // vL1 only
            }
            __syncthreads();
        }
    }
}

// ---------------------------------------------------------------------------
// Logits: p[b][cls] = h[b,:] . W_ph[cls,:] + b_p[cls]; log_softmax over 10.
// ---------------------------------------------------------------------------
__global__ __launch_bounds__(256) void logits_kernel(
    const u16* __restrict__ hT, const float* __restrict__ Wph,
    const float* __restrict__ bp, float* __restrict__ out)
{
    const int wave = threadIdx.x >> 6;
    const int lane = threadIdx.x & 63;
    const int b = blockIdx.x * 4 + wave;

    const u16* hp = hT + (size_t)b * kH + lane * 16;
    float hf[16];
#pragma unroll
    for (int j = 0; j < 16; ++j) hf[j] = b2f(hp[j]);

    float p[kC];
#pragma unroll
    for (int cls = 0; cls < kC; ++cls) {
        const float* wp = Wph + (size_t)cls * kH + lane * 16;
        float s = 0.f;
#pragma unroll
        for (int j = 0; j < 16; ++j) s += hf[j] * wp[j];
#pragma unroll
        for (int off = 1; off < 64; off <<= 1) s += __shfl_xor(s, off, 64);
        p[cls] = fminf(fmaxf(s + bp[cls], -1.0e4f), 1.0e4f);
    }

    float m = p[0];
#pragma unroll
    for (int cls = 1; cls < kC; ++cls) m = fmaxf(m, p[cls]);
    float se = 0.f;
#pragma unroll
    for (int cls = 0; cls < kC; ++cls) se += __expf(p[cls] - m);
    float l = m + __logf(se);

    if (lane < kC) {
        float myp = p[0];
#pragma unroll
        for (int cls = 1; cls < kC; ++cls)
            if (lane == cls) myp = p[cls];
        out[(size_t)b * kC + lane] = myp - l;
    }
}

// ---------------------------------------------------------------------------
extern "C" void kernel_launch(void* const* d_in, const int* in_sizes, int n_in,
                              void* d_out, int out_size, void* d_ws, size_t ws_size,
                              hipStream_t stream)
{
    const int*   x   = (const int*)  d_in[0];
    const float* emb = (const float*)d_in[1];
    const float* Wgx = (const float*)d_in[2];
    const float* Wgh = (const float*)d_in[3];
    const float* bg  = (const float*)d_in[4];
    const float* Wix = (const float*)d_in[5];
    const float* Wih = (const float*)d_in[6];
    const float* bi  = (const float*)d_in[7];
    const float* Wfx = (const float*)d_in[8];
    const float* Wfh = (const float*)d_in[9];
    const float* bf_ = (const float*)d_in[10];
    const float* Wox = (const float*)d_in[11];
    const float* Woh = (const float*)d_in[12];
    const float* bo  = (const float*)d_in[13];
    const float* Wph = (const float*)d_in[14];
    const float* bp  = (const float*)d_in[15];
    const float* h0  = (const float*)d_in[16];
    const float* c0  = (const float*)d_in[17];

    char* ws = (char*)d_ws;
    float* Qp  = (float*)ws;                              // 64 KB
    u16*   hA  = (u16*)(ws + (64 << 10));                 // 2 MB
    u16*   hB  = hA + (size_t)kB * kH;                    // 2 MB
    float* cT  = (float*)(hB + (size_t)kB * kH);          // 4 MB
    u16*   wsw = (u16*)(cT + (size_t)kB * kH);            // 8 MB
    int*   ctrl = (int*)(wsw + (size_t)64 * 65536);       // 2 KB (total ~16.07 MB)

    prep_weights<<<dim3(2048), dim3(256), 0, stream>>>(Wgh, Wih, Wfh, Woh, wsw);
    prep_hc<<<dim3(kB / 32, kH / 32), dim3(32, 32), 0, stream>>>(h0, c0, hA, cT);
    prep_q<<<dim3(16), dim3(256), 0, stream>>>(Wgx, Wix, Wfx, Wox, bg, bi, bf_, bo,
                                               emb, Qp, ctrl);

    lstm_persist<<<dim3(256), dim3(512), 0, stream>>>(
        wsw, Qp, x, (short*)hA, (short*)hB, cT, ctrl);

    // 127 steps: t=126 (even) wrote hB.
    logits_kernel<<<dim3(kB / 4), dim3(256), 0, stream>>>(hB, Wph, bp, (float*)d_out);
}